// Round 3
// baseline (814.641 us; speedup 1.0000x reference)
//
#include <hip/hip_runtime.h>
#include <stdint.h>
#include <stddef.h>
#include <math.h>

// WindowAttention MI355X (gfx950). B=16 C=512 H=W=64 WS=16 HEADS=8 d=64.
// L=256 windows, N=256 positions, attention batches (n,h)=2048 of 256x256,d=64.
// Workspace: q 67MB (o in-place) | k 67MB | v 67MB | w1b 1.5MB | w2b 0.5MB.

typedef __bf16 bf16;
typedef __attribute__((ext_vector_type(8))) __bf16 bf16x8;
typedef __attribute__((ext_vector_type(4))) __bf16 bf16x4;
typedef __attribute__((ext_vector_type(4))) float f32x4;

#define MFMA16(A, B, C) __builtin_amdgcn_mfma_f32_16x16x32_bf16((A), (B), (C), 0, 0, 0)

__device__ __forceinline__ float fast_exp2(float x) {
#if __has_builtin(__builtin_amdgcn_exp2f)
  return __builtin_amdgcn_exp2f(x);
#else
  return exp2f(x);
#endif
}

// XOR-swizzled A-tile: 128 rows x 512 cols bf16, 131072 B. granule(16B) ^= row bits.
__device__ __forceinline__ int aswz(int n, int c) {
  int g = (c >> 3) ^ ((n >> 4) & 7) ^ (n & 7);
  return n * 512 + (g << 3) + (c & 7);
}

// ---------------------------------------------------------------- cvt weights
__global__ void cvt_fp32_bf16(const float* __restrict__ src, bf16* __restrict__ dst) {
  int i = (blockIdx.x * blockDim.x + threadIdx.x) * 4;
  float4 f = *(const float4*)(src + i);
  bf16x4 r;
  r[0] = (bf16)f.x; r[1] = (bf16)f.y; r[2] = (bf16)f.z; r[3] = (bf16)f.w;
  *(bf16x4*)(dst + i) = r;
}

// ---------------------------------------------------------------- QKV GEMM
// 1024 thr = 16 waves (2 row-groups x 8 cout-columns), A[128][512] resident.
// Swapped MFMA: D rows = cout, cols = n -> b64 epilogue packs.
// Chunks nc=0,1,2 map exactly to q,k,v; wc maps to head hh.
__global__ void __launch_bounds__(1024, 4) gemm_qkv(
    const float* __restrict__ x, const bf16* __restrict__ w1,
    const float* __restrict__ b1,
    bf16* __restrict__ qo, bf16* __restrict__ ko, bf16* __restrict__ vo) {
  extern __shared__ bf16 Al[];              // 128*512 swizzled
  bf16* Ep = Al + 128 * 512;                // 8 bufs x [16][72]
  const int tid = threadIdx.x;
  const int bm  = blockIdx.x;               // 0..511
  const int l   = bm >> 1;
  const int n0  = (bm & 1) << 7;
  const int b   = l >> 4, ih = (l >> 2) & 3, iw = l & 3;
  const int h0  = ih * 16 + (n0 >> 4);
  const int w0  = iw * 16;

  for (int j = 0; j < 16; ++j) {            // stage A: fp32 gather -> bf16 LDS
    int f4  = j * 1024 + tid;               // 0..16383
    int c   = f4 >> 5;
    int qq  = f4 & 31;
    int wsh = qq >> 2;
    int w4  = (qq & 3) << 2;
    float4 xf = *(const float4*)(x + (((b * 512 + c) * 64 + h0 + wsh) * 64 + w0 + w4));
    int nb = wsh * 16 + w4;
    Al[aswz(nb + 0, c)] = (bf16)xf.x;
    Al[aswz(nb + 1, c)] = (bf16)xf.y;
    Al[aswz(nb + 2, c)] = (bf16)xf.z;
    Al[aswz(nb + 3, c)] = (bf16)xf.w;
  }
  __syncthreads();

  const int wave = tid >> 6, lane = tid & 63;
  const int l15 = lane & 15, quad = lane >> 4;
  const int wr = wave >> 3, wc = wave & 7;   // 2x8 wave grid, wave tile 64n x 64cout
  const int R = wr * 64;
  const f32x4 fz = {0.f, 0.f, 0.f, 0.f};

  for (int nc = 0; nc < 3; ++nc) {
    const int t0w = nc * 512 + wc * 64;      // which = nc, hh = wc (both uniform)
    f32x4 acc[4][4];
#pragma unroll
    for (int a = 0; a < 4; ++a)
#pragma unroll
      for (int c2 = 0; c2 < 4; ++c2) acc[a][c2] = fz;

    bf16x8 bfr[4];
#pragma unroll
    for (int ct = 0; ct < 4; ++ct)
      bfr[ct] = *(const bf16x8*)&w1[(size_t)(t0w + ct * 16 + l15) * 512 + quad * 8];
#pragma unroll
    for (int ks = 0; ks < 16; ++ks) {
      bf16x8 bnx[4];
      if (ks < 15) {
#pragma unroll
        for (int ct = 0; ct < 4; ++ct)
          bnx[ct] = *(const bf16x8*)&w1[(size_t)(t0w + ct * 16 + l15) * 512 + (ks + 1) * 32 + quad * 8];
      }
      bf16x8 af[4];
#pragma unroll
      for (int lt = 0; lt < 4; ++lt)
        af[lt] = *(const bf16x8*)&Al[aswz(R + lt * 16 + l15, ks * 32 + quad * 8)];
#pragma unroll
      for (int lt = 0; lt < 4; ++lt)
#pragma unroll
        for (int ct = 0; ct < 4; ++ct)
          acc[lt][ct] = MFMA16(bfr[ct], af[lt], acc[lt][ct]);  // rows=cout, cols=n
#pragma unroll
      for (int ct = 0; ct < 4; ++ct) bfr[ct] = bnx[ct];
    }

    bf16* dst = (nc == 0) ? qo : (nc == 1) ? ko : vo;
    const float scale = (nc == 0) ? 0.125f : 1.0f;

#pragma unroll
    for (int phase = 0; phase < 2; ++phase) {
      __syncthreads();
      if (wr == phase) {
        bf16* Epw = Ep + wc * 16 * 72;
#pragma unroll
        for (int lt = 0; lt < 4; ++lt) {
#pragma unroll
          for (int ct = 0; ct < 4; ++ct) {
            float4 bias4 = *(const float4*)&b1[t0w + ct * 16 + quad * 4];
            bf16x4 pk;
#pragma unroll
            for (int r = 0; r < 4; ++r)
              pk[r] = (bf16)((acc[lt][ct][r] + ((const float*)&bias4)[r]) * scale);
            *(bf16x4*)&Epw[l15 * 72 + ct * 16 + quad * 4] = pk;  // b64
          }
          const int rr = lane >> 3, ch8 = (lane & 7) * 8;
#pragma unroll
          for (int hf = 0; hf < 2; ++hf) {
            int row = hf * 8 + rr;
            bf16x8 vv = *(const bf16x8*)&Epw[row * 72 + ch8];
            int n = n0 + R + lt * 16 + row;
            *(bf16x8*)&dst[((size_t)(n * 8 + wc) * 256 + l) * 64 + ch8] = vv;
          }
        }
      }
    }
  }
}

// ---------------------------------------------------------------- attention
// One block (512 thr) per (n,h). K LDS [256][72], V^T LDS [64][264],
// per-wave P [16][264]. Swapped MFMA: QK^T D rows=m cols=q; PV D rows=d cols=q.
// pf for both 16-row tiles kept in regs -> each V^T frag read once.
__global__ void __launch_bounds__(512, 2) attn_win(
    bf16* __restrict__ qio, const bf16* __restrict__ kg, const bf16* __restrict__ vg) {
  extern __shared__ bf16 sm[];
  bf16* Kl = sm;
  bf16* Vt = sm + 256 * 72;
  bf16* Pl = Vt + 64 * 264;
  const int tid = threadIdx.x;
  const int bb = blockIdx.x;
  const int n = bb >> 3, h = bb & 7;
  const size_t base = (size_t)(n * 8 + h) * 16384;
  const bf16* Kg = kg + base;
  const bf16* Vg = vg + base;
  bf16* Qg = qio + base;

  for (int j = 0; j < 4; ++j) {             // K: [m][d] -> [m][72]
    int cc = j * 512 + tid;
    int m = cc >> 3, dc = cc & 7;
    bf16x8 t = *(const bf16x8*)(Kg + m * 64 + dc * 8);
    *(bf16x8*)&Kl[m * 72 + dc * 8] = t;
  }
  for (int j = 0; j < 4; ++j) {             // V: [m][d] -> V^T [d][264]
    int cc = j * 512 + tid;
    int dc = cc >> 8, m = cc & 255;
    bf16x8 t = *(const bf16x8*)(Vg + m * 64 + dc * 8);
#pragma unroll
    for (int s = 0; s < 8; ++s) Vt[(dc * 8 + s) * 264 + m] = t[s];
  }

  const int wave = tid >> 6, lane = tid & 63;
  const int l15 = lane & 15, quad = lane >> 4;
  const int lb = wave * 32;
  bf16* Pw = Pl + wave * 16 * 264;

  bf16x8 qf[2][2];
#pragma unroll
  for (int lt = 0; lt < 2; ++lt)
#pragma unroll
    for (int ks = 0; ks < 2; ++ks)
      qf[lt][ks] = *(const bf16x8*)(Qg + (lb + lt * 16 + l15) * 64 + ks * 32 + quad * 8);

  __syncthreads();

  const f32x4 fz = {0.f, 0.f, 0.f, 0.f};
  const float LOG2E = 1.44269504088896340736f;
  float inv[2];
  bf16x8 pf[2][8];

#pragma unroll
  for (int lt = 0; lt < 2; ++lt) {
    f32x4 s[16];
#pragma unroll
    for (int mt = 0; mt < 16; ++mt) s[mt] = fz;
#pragma unroll
    for (int mt = 0; mt < 16; ++mt)
#pragma unroll
      for (int ks = 0; ks < 2; ++ks) {
        bf16x8 kf = *(const bf16x8*)&Kl[(mt * 16 + l15) * 72 + ks * 32 + quad * 8];
        s[mt] = MFMA16(kf, qf[lt][ks], s[mt]);  // rows=m, cols=q
      }
    // per-lane: 64 scores of q=l15 (m = mt*16 + quad*4 + r); reduce + 2 shfl
    float mx = s[0][0];
#pragma unroll
    for (int mt = 0; mt < 16; ++mt)
#pragma unroll
      for (int r = 0; r < 4; ++r) mx = fmaxf(mx, s[mt][r]);
    mx = fmaxf(mx, __shfl_xor(mx, 16));
    mx = fmaxf(mx, __shfl_xor(mx, 32));
    float sum = 0.f;
#pragma unroll
    for (int mt = 0; mt < 16; ++mt) {
      bf16x4 pk;
#pragma unroll
      for (int r = 0; r < 4; ++r) {
        float p = fast_exp2((s[mt][r] - mx) * LOG2E);
        bf16 pb = (bf16)p;
        sum += (float)pb;
        pk[r] = pb;
      }
      *(bf16x4*)&Pw[l15 * 264 + mt * 16 + quad * 4] = pk;  // b64, rows=q
    }
    sum += __shfl_xor(sum, 16);
    sum += __shfl_xor(sum, 32);
    inv[lt] = 1.0f / sum;
#pragma unroll
    for (int mk = 0; mk < 8; ++mk)
      pf[lt][mk] = *(const bf16x8*)&Pw[l15 * 264 + mk * 32 + quad * 8];
  }

  f32x4 of[2][4];
#pragma unroll
  for (int lt = 0; lt < 2; ++lt)
#pragma unroll
    for (int dt = 0; dt < 4; ++dt) of[lt][dt] = fz;
#pragma unroll
  for (int dt = 0; dt < 4; ++dt)
#pragma unroll
    for (int mk = 0; mk < 8; ++mk) {
      bf16x8 vf = *(const bf16x8*)&Vt[(dt * 16 + l15) * 264 + mk * 32 + quad * 8];
      of[0][dt] = MFMA16(vf, pf[0][mk], of[0][dt]);  // rows=d, cols=q
      of[1][dt] = MFMA16(vf, pf[1][mk], of[1][dt]);
    }

#pragma unroll
  for (int lt = 0; lt < 2; ++lt) {
#pragma unroll
    for (int dt = 0; dt < 4; ++dt) {
      bf16x4 pk;
#pragma unroll
      for (int r = 0; r < 4; ++r) pk[r] = (bf16)(of[lt][dt][r] * inv[lt]);
      *(bf16x4*)&Pw[l15 * 264 + dt * 16 + quad * 4] = pk;  // b64, rows=q
    }
    const int rr = lane >> 3, ch8 = (lane & 7) * 8;
#pragma unroll
    for (int hf = 0; hf < 2; ++hf) {
      int row = hf * 8 + rr;
      bf16x8 vv = *(const bf16x8*)&Pw[row * 264 + ch8];
      *(bf16x8*)(Qg + (lb + lt * 16 + row) * 64 + ch8) = vv;
    }
  }
}

// ---------------------------------------------------------------- out proj
// 1024 thr = 16 waves (2x8), single cout chunk of 512. Swapped MFMA -> direct
// 64B-contiguous fp32 stores along w.
__global__ void __launch_bounds__(1024, 4) gemm_out(
    const bf16* __restrict__ og, const bf16* __restrict__ w2,
    const float* __restrict__ b2, float* __restrict__ out) {
  extern __shared__ bf16 Al[];  // 128*512 swizzled
  const int tid = threadIdx.x;
  const int bm = blockIdx.x;
  const int l = bm >> 1;
  const int n0 = (bm & 1) << 7;
  const int b = l >> 4, ih = (l >> 2) & 3, iw = l & 3;

  for (int j = 0; j < 8; ++j) {  // o[n][h][l][d] gather -> swizzled LDS
    int cc = j * 1024 + tid;
    int nl = cc >> 6;
    int ch = cc & 63;
    int hh = ch >> 3, d8 = (ch & 7) * 8;
    bf16x8 t = *(const bf16x8*)(og + ((size_t)((n0 + nl) * 8 + hh) * 256 + l) * 64 + d8);
    *(bf16x8*)&Al[aswz(nl, ch * 8)] = t;
  }
  __syncthreads();

  const int wave = tid >> 6, lane = tid & 63;
  const int l15 = lane & 15, quad = lane >> 4;
  const int wr = wave >> 3, wc = wave & 7;
  const int R = wr * 64;
  const int t0w = wc * 64;
  const f32x4 fz = {0.f, 0.f, 0.f, 0.f};

  f32x4 acc[4][4];
#pragma unroll
  for (int a = 0; a < 4; ++a)
#pragma unroll
    for (int c2 = 0; c2 < 4; ++c2) acc[a][c2] = fz;

  bf16x8 bfr[4];
#pragma unroll
  for (int ct = 0; ct < 4; ++ct)
    bfr[ct] = *(const bf16x8*)&w2[(size_t)(t0w + ct * 16 + l15) * 512 + quad * 8];
#pragma unroll
  for (int ks = 0; ks < 16; ++ks) {
    bf16x8 bnx[4];
    if (ks < 15) {
#pragma unroll
      for (int ct = 0; ct < 4; ++ct)
        bnx[ct] = *(const bf16x8*)&w2[(size_t)(t0w + ct * 16 + l15) * 512 + (ks + 1) * 32 + quad * 8];
    }
    bf16x8 af[4];
#pragma unroll
    for (int lt = 0; lt < 4; ++lt)
      af[lt] = *(const bf16x8*)&Al[aswz(R + lt * 16 + l15, ks * 32 + quad * 8)];
#pragma unroll
    for (int lt = 0; lt < 4; ++lt)
#pragma unroll
      for (int ct = 0; ct < 4; ++ct)
        acc[lt][ct] = MFMA16(bfr[ct], af[lt], acc[lt][ct]);  // rows=cout, cols=n
#pragma unroll
    for (int ct = 0; ct < 4; ++ct) bfr[ct] = bnx[ct];
  }

#pragma unroll
  for (int ct = 0; ct < 4; ++ct) {
    float4 bias4 = *(const float4*)&b2[t0w + ct * 16 + quad * 4];
#pragma unroll
    for (int lt = 0; lt < 4; ++lt) {
      const int nbase = n0 + R + lt * 16;   // l15 spans w; wsh uniform
      const int wsh = nbase >> 4;
      size_t rowbase = (((size_t)b * 512) * 64 + (size_t)ih * 16 + wsh) * 64 + iw * 16 + l15;
#pragma unroll
      for (int r = 0; r < 4; ++r) {
        int cout = t0w + ct * 16 + quad * 4 + r;
        out[rowbase + (size_t)cout * 4096] = acc[lt][ct][r] + ((const float*)&bias4)[r];
      }
    }
  }
}

// ---------------------------------------------------------------- launch
extern "C" void kernel_launch(void* const* d_in, const int* in_sizes, int n_in,
                              void* d_out, int out_size, void* d_ws, size_t ws_size,
                              hipStream_t stream) {
  (void)in_sizes; (void)n_in; (void)out_size; (void)ws_size;
  const float* x   = (const float*)d_in[0];
  const float* w1f = (const float*)d_in[1];
  const float* b1  = (const float*)d_in[2];
  const float* w2f = (const float*)d_in[3];
  const float* b2  = (const float*)d_in[4];
  float* out = (float*)d_out;

  char* ws = (char*)d_ws;
  bf16* q   = (bf16*)(ws);
  bf16* k   = (bf16*)(ws + 67108864ull);
  bf16* v   = (bf16*)(ws + 134217728ull);
  bf16* w1b = (bf16*)(ws + 201326592ull);
  bf16* w2b = (bf16*)(ws + 201326592ull + 1572864ull);

  const int LDS_QKV  = (128 * 512 + 8 * 16 * 72) * 2;             // 149,504 B
  const int LDS_ATTN = (256 * 72 + 64 * 264 + 8 * 16 * 264) * 2;  // 138,240 B
  const int LDS_OUT  = 128 * 512 * 2;                             // 131,072 B
  hipFuncSetAttribute(reinterpret_cast<const void*>(gemm_qkv),
                      hipFuncAttributeMaxDynamicSharedMemorySize, LDS_QKV);
  hipFuncSetAttribute(reinterpret_cast<const void*>(attn_win),
                      hipFuncAttributeMaxDynamicSharedMemorySize, LDS_ATTN);
  hipFuncSetAttribute(reinterpret_cast<const void*>(gemm_out),
                      hipFuncAttributeMaxDynamicSharedMemorySize, LDS_OUT);

  hipLaunchKernelGGL(cvt_fp32_bf16, dim3(768), dim3(256), 0, stream, w1f, w1b);
  hipLaunchKernelGGL(cvt_fp32_bf16, dim3(256), dim3(256), 0, stream, w2f, w2b);
  hipLaunchKernelGGL(gemm_qkv, dim3(512), dim3(1024), LDS_QKV, stream, x, w1b, b1, q, k, v);
  hipLaunchKernelGGL(attn_win, dim3(2048), dim3(512), LDS_ATTN, stream, q, k, v);
  hipLaunchKernelGGL(gemm_out, dim3(512), dim3(1024), LDS_OUT, stream, q, w2b, b2, out);
}